// Round 1
// baseline (276.158 us; speedup 1.0000x reference)
//
#include <hip/hip_runtime.h>

#define SEQ   2048
#define NSEG  24          // 3 ngram sizes * 8 heads
#define POS_PER_WG 64

__device__ __forceinline__ float4 ld4(const float* __restrict__ p) {
    return *reinterpret_cast<const float4*>(p);
}

__global__ __launch_bounds__(1024) void engram_fused(
    const int*   __restrict__ tok,
    const float* __restrict__ hidden,
    const float* __restrict__ tab2, const int* __restrict__ mul2,
    const float* __restrict__ tab3, const int* __restrict__ mul3,
    const float* __restrict__ tab4, const int* __restrict__ mul4,
    const float* __restrict__ Wq, const float* __restrict__ bq,
    const float* __restrict__ Wk, const float* __restrict__ bk,
    const float* __restrict__ Wv, const float* __restrict__ bv,
    const float* __restrict__ Wo, const float* __restrict__ bo,
    float* __restrict__ out, float* __restrict__ gate_out)
{
    __shared__ int idx_lds[NSEG][POS_PER_WG];
    __shared__ __align__(16) char emb[2][POS_PER_WG * 256];   // 2 x 16 KB (fp32 rows of 64)
    __shared__ float gpart[16][POS_PER_WG];

    const int t     = threadIdx.x;
    const int pbase = blockIdx.x * POS_PER_WG;

    // ---------------- Phase 0: n-gram hash indices (exact int64 math) -------------
    if (t < POS_PER_WG) {
        const int pos = pbase + t;
        const int s   = pos & (SEQ - 1);
        const int b   = pos >> 11;
        const int* tr = tok + (size_t)b * SEQ;
        const unsigned long long t3 = (unsigned long long)tr[s];
        const unsigned long long t2 = (s >= 1) ? (unsigned long long)tr[s - 1] : 0ull;
        const unsigned long long t1 = (s >= 2) ? (unsigned long long)tr[s - 2] : 0ull;
        const unsigned long long t0 = (s >= 3) ? (unsigned long long)tr[s - 3] : 0ull;
        // n=2, prime 100003 (tokens < prime, so no pre-mod needed)
        for (int h = 0; h < 8; ++h) {
            unsigned long long m = (unsigned long long)mul2[h];
            unsigned long long hh = (t2 * m + t3) % 100003ull;
            idx_lds[h][t] = (s >= 1) ? (int)hh : -1;
        }
        // n=3, prime 100019
        for (int h = 0; h < 8; ++h) {
            unsigned long long m = (unsigned long long)mul3[h];
            unsigned long long hh = (t1 * m + t2) % 100019ull;
            hh = (hh * m + t3) % 100019ull;
            idx_lds[8 + h][t] = (s >= 2) ? (int)hh : -1;
        }
        // n=4, prime 100043
        for (int h = 0; h < 8; ++h) {
            unsigned long long m = (unsigned long long)mul4[h];
            unsigned long long hh = (t0 * m + t1) % 100043ull;
            hh = (hh * m + t2) % 100043ull;
            hh = (hh * m + t3) % 100043ull;
            idx_lds[16 + h][t] = (s >= 3) ? (int)hh : -1;
        }
    }
    __syncthreads();

    // gather role: row (position-in-block) + 16B chunk
    const int gr = t >> 4;      // 0..63
    const int gc = t & 15;      // 0..15

    auto fetch = [&](int seg) -> float4 {
        const int idx = idx_lds[seg][gr];
        float4 z; z.x = z.y = z.z = z.w = 0.0f;
        if (idx < 0) return z;
        const int ni = seg >> 3, h = seg & 7;
        const float* tabp;
        int prime;
        if (ni == 0)      { tabp = tab2; prime = 100003; }
        else if (ni == 1) { tabp = tab3; prime = 100019; }
        else              { tabp = tab4; prime = 100043; }
        const float* row = tabp + ((size_t)h * prime + idx) * 64;
        return ld4(row + gc * 4);
    };

    // compute role: lane = position, wave owns 4 output dims
    const int p  = t & 63;
    const int w4 = __builtin_amdgcn_readfirstlane(t >> 6) * 4;
    const int psw = (p & 7) << 4;           // XOR swizzle for this lane's row

    float4 kacc; kacc.x = kacc.y = kacc.z = kacc.w = 0.0f;
    float4 vacc; vacc.x = vacc.y = vacc.z = vacc.w = 0.0f;

    // ---------------- Main loop: 24 segments, double-buffered LDS -----------------
    float4 cur = fetch(0);
#pragma unroll 1
    for (int seg = 0; seg < NSEG; ++seg) {
        float4 nxt;
        if (seg < NSEG - 1) nxt = fetch(seg + 1);
        else { nxt.x = nxt.y = nxt.z = nxt.w = 0.0f; }

        {   // staged (swizzled) write of this segment's gathered rows
            char* wb = emb[seg & 1];
            *reinterpret_cast<float4*>(wb + gr * 256 + ((gc * 16) ^ ((gr & 7) << 4))) = cur;
        }
        __syncthreads();

        const char*  rb     = emb[seg & 1];
        const float* wkbase = Wk + (seg << 6) * 64 + w4;   // row (seg*64+i), cols [w4..w4+4)
        const float* wvbase = Wv + (seg << 6) * 64 + w4;
#pragma unroll
        for (int i0 = 0; i0 < 16; ++i0) {
            const float4 e = *reinterpret_cast<const float4*>(rb + p * 256 + ((i0 * 16) ^ psw));
#pragma unroll
            for (int u = 0; u < 4; ++u) {
                const int i = i0 * 4 + u;
                const float4 wk = ld4(wkbase + i * 64);
                const float4 wv = ld4(wvbase + i * 64);
                const float ev = (u == 0) ? e.x : (u == 1) ? e.y : (u == 2) ? e.z : e.w;
                kacc.x += ev * wk.x; kacc.y += ev * wk.y; kacc.z += ev * wk.z; kacc.w += ev * wk.w;
                vacc.x += ev * wv.x; vacc.y += ev * wv.y; vacc.z += ev * wv.z; vacc.w += ev * wv.w;
            }
        }
        cur = nxt;
    }

    // biases
    {
        const float4 bk4 = ld4(bk + w4);
        kacc.x += bk4.x; kacc.y += bk4.y; kacc.z += bk4.z; kacc.w += bk4.w;
        const float4 bv4 = ld4(bv + w4);
        vacc.x += bv4.x; vacc.y += bv4.y; vacc.z += bv4.z; vacc.w += bv4.w;
    }

    // ---------------- Epilogue: q, gate, out ----------------
    // stage hidden rows (swizzled) into emb[0]; safe: last compute read emb[1]
    {
        const float4 hv = ld4(hidden + (size_t)(pbase + gr) * 64 + gc * 4);
        *reinterpret_cast<float4*>(emb[0] + gr * 256 + ((gc * 16) ^ ((gr & 7) << 4))) = hv;
    }
    __syncthreads();

    // q = hidden @ Wq + bq  (this wave's 4 dims)
    float4 qacc = ld4(bq + w4);
#pragma unroll
    for (int i0 = 0; i0 < 16; ++i0) {
        const float4 e = *reinterpret_cast<const float4*>(emb[0] + p * 256 + ((i0 * 16) ^ psw));
#pragma unroll
        for (int u = 0; u < 4; ++u) {
            const int i = i0 * 4 + u;
            const float4 wq = ld4(Wq + i * 64 + w4);
            const float ev = (u == 0) ? e.x : (u == 1) ? e.y : (u == 2) ? e.z : e.w;
            qacc.x += ev * wq.x; qacc.y += ev * wq.y; qacc.z += ev * wq.z; qacc.w += ev * wq.w;
        }
    }
    // partial q.k over this wave's dims
    gpart[t >> 6][p] = qacc.x * kacc.x + qacc.y * kacc.y + qacc.z * kacc.z + qacc.w * kacc.w;
    // park v (transposed via swizzled LDS) — everyone passed the barrier above,
    // so emb[1] is no longer being read
    *reinterpret_cast<float4*>(emb[1] + p * 256 + ((w4 * 4) ^ psw)) = vacc;
    __syncthreads();

    float g = 0.0f;
#pragma unroll
    for (int j = 0; j < 16; ++j) g += gpart[j][p];
    const float gate = 1.0f / (1.0f + expf(-g * 0.125f));

    // out = gate * (v @ Wo) + bo
    float4 oacc; oacc.x = oacc.y = oacc.z = oacc.w = 0.0f;
#pragma unroll
    for (int i0 = 0; i0 < 16; ++i0) {
        const float4 e = *reinterpret_cast<const float4*>(emb[1] + p * 256 + ((i0 * 16) ^ psw));
#pragma unroll
        for (int u = 0; u < 4; ++u) {
            const int i = i0 * 4 + u;
            const float4 wo = ld4(Wo + i * 64 + w4);
            const float ev = (u == 0) ? e.x : (u == 1) ? e.y : (u == 2) ? e.z : e.w;
            oacc.x += ev * wo.x; oacc.y += ev * wo.y; oacc.z += ev * wo.z; oacc.w += ev * wo.w;
        }
    }
    const float4 bo4 = ld4(bo + w4);
    float4 res;
    res.x = gate * oacc.x + bo4.x;
    res.y = gate * oacc.y + bo4.y;
    res.z = gate * oacc.z + bo4.z;
    res.w = gate * oacc.w + bo4.w;
    *reinterpret_cast<float4*>(out + (size_t)(pbase + p) * 64 + w4) = res;

    if (t < POS_PER_WG) gate_out[pbase + t] = gate;
}

extern "C" void kernel_launch(void* const* d_in, const int* in_sizes, int n_in,
                              void* d_out, int out_size, void* d_ws, size_t ws_size,
                              hipStream_t stream) {
    const int*   tok    = (const int*)  d_in[0];
    const float* hidden = (const float*)d_in[1];
    const float* tab2   = (const float*)d_in[2];
    const int*   mul2   = (const int*)  d_in[3];
    const float* tab3   = (const float*)d_in[4];
    const int*   mul3   = (const int*)  d_in[5];
    const float* tab4   = (const float*)d_in[6];
    const int*   mul4   = (const int*)  d_in[7];
    const float* Wq     = (const float*)d_in[8];
    const float* bq     = (const float*)d_in[9];
    const float* Wk     = (const float*)d_in[10];
    const float* bk     = (const float*)d_in[11];
    const float* Wv     = (const float*)d_in[12];
    const float* bv     = (const float*)d_in[13];
    const float* Wo     = (const float*)d_in[14];
    const float* bo     = (const float*)d_in[15];

    float* out      = (float*)d_out;
    float* gate_out = out + (size_t)16384 * 64;   // B*S*D, then gate B*S

    hipLaunchKernelGGL(engram_fused, dim3(16384 / POS_PER_WG), dim3(1024), 0, stream,
                       tok, hidden, tab2, mul2, tab3, mul3, tab4, mul4,
                       Wq, bq, Wk, bk, Wv, bv, Wo, bo, out, gate_out);
}

// Round 2
// 158.943 us; speedup vs baseline: 1.7375x; 1.7375x over previous
//
#include <hip/hip_runtime.h>

#define SEQ   2048
#define NSEG  24          // 3 ngram sizes * 8 heads
#define POS_PER_WG 64

__device__ __forceinline__ float4 ld4(const float* __restrict__ p) {
    return *reinterpret_cast<const float4*>(p);
}

__global__ __launch_bounds__(1024) void engram_fused(
    const int*   __restrict__ tok,
    const float* __restrict__ hidden,
    const float* __restrict__ tab2, const int* __restrict__ mul2,
    const float* __restrict__ tab3, const int* __restrict__ mul3,
    const float* __restrict__ tab4, const int* __restrict__ mul4,
    const float* __restrict__ Wq, const float* __restrict__ bq,
    const float* __restrict__ Wk, const float* __restrict__ bk,
    const float* __restrict__ Wv, const float* __restrict__ bv,
    const float* __restrict__ Wo, const float* __restrict__ bo,
    float* __restrict__ out, float* __restrict__ gate_out)
{
    // single-buffered tiles; double-barrier per segment handles WAR
    __shared__ int idx_lds[NSEG][POS_PER_WG];                  // 6 KB
    __shared__ __align__(16) char  emb[POS_PER_WG * 256];      // 16 KB (64 pos x 64 f32, swizzled)
    __shared__ __align__(16) float wk_lds[64][64];             // 16 KB (current seg Wk tile)
    __shared__ __align__(16) float wv_lds[64][64];             // 16 KB
    __shared__ float gpart[16][64];                            // 4 KB

    const int t     = threadIdx.x;
    const int pbase = blockIdx.x * POS_PER_WG;

    // ---------------- Phase 0: n-gram hash indices (exact int64 math) -------------
    if (t < 192) {
        const int grp = t >> 6;     // 0: n=2, 1: n=3, 2: n=4
        const int r   = t & 63;
        const int pos = pbase + r;
        const int s   = pos & (SEQ - 1);
        const int b   = pos >> 11;
        const int* tr = tok + (size_t)b * SEQ;
        const unsigned long long t3 = (unsigned long long)tr[s];
        const unsigned long long t2 = (s >= 1) ? (unsigned long long)tr[s - 1] : 0ull;
        const unsigned long long t1 = (s >= 2) ? (unsigned long long)tr[s - 2] : 0ull;
        const unsigned long long t0 = (s >= 3) ? (unsigned long long)tr[s - 3] : 0ull;
        if (grp == 0) {
            for (int h = 0; h < 8; ++h) {
                unsigned long long m = (unsigned long long)mul2[h];
                unsigned long long hh = (t2 * m + t3) % 100003ull;
                idx_lds[h][r] = (s >= 1) ? (int)hh : -1;
            }
        } else if (grp == 1) {
            for (int h = 0; h < 8; ++h) {
                unsigned long long m = (unsigned long long)mul3[h];
                unsigned long long hh = (t1 * m + t2) % 100019ull;
                hh = (hh * m + t3) % 100019ull;
                idx_lds[8 + h][r] = (s >= 2) ? (int)hh : -1;
            }
        } else {
            for (int h = 0; h < 8; ++h) {
                unsigned long long m = (unsigned long long)mul4[h];
                unsigned long long hh = (t0 * m + t1) % 100043ull;
                hh = (hh * m + t2) % 100043ull;
                hh = (hh * m + t3) % 100043ull;
                idx_lds[16 + h][r] = (s >= 3) ? (int)hh : -1;
            }
        }
    }
    __syncthreads();

    // staging roles
    const int gr = t >> 4;      // 0..63 : position row
    const int gc = t & 15;      // 0..15 : 16B chunk within row

    auto fetch = [&](int seg) -> float4 {
        const int idx = idx_lds[seg][gr];
        float4 z; z.x = z.y = z.z = z.w = 0.0f;
        if (idx < 0) return z;
        const int ni = seg >> 3, h = seg & 7;
        const float* tabp;
        int prime;
        if (ni == 0)      { tabp = tab2; prime = 100003; }
        else if (ni == 1) { tabp = tab3; prime = 100019; }
        else              { tabp = tab4; prime = 100043; }
        const float* row = tabp + ((size_t)h * prime + idx) * 64;
        return ld4(row + gc * 4);
    };

    auto stage = [&](float4 e, float4 wk, float4 wv) {
        *reinterpret_cast<float4*>(emb + gr * 256 + ((gc * 16) ^ ((gr & 7) << 4))) = e;
        *reinterpret_cast<float4*>(reinterpret_cast<char*>(wk_lds) + t * 16) = wk;
        *reinterpret_cast<float4*>(reinterpret_cast<char*>(wv_lds) + t * 16) = wv;
    };

    // compute roles: lane = position, wave owns 4 output dims
    const int p   = t & 63;
    const int w4  = __builtin_amdgcn_readfirstlane(t >> 6) * 4;
    const int psw = (p & 7) << 4;

    float4 kacc; kacc.x = kacc.y = kacc.z = kacc.w = 0.0f;
    float4 vacc; vacc.x = vacc.y = vacc.z = vacc.w = 0.0f;

    // ---------------- prologue: stage segment 0 -----------------------------------
    {
        float4 g0 = fetch(0);
        float4 k0 = ld4(Wk + 0 + (size_t)t * 4);   // seg 0 tile, linear 16B/thread
        float4 v0 = ld4(Wv + 0 + (size_t)t * 4);
        stage(g0, k0, v0);
    }
    __syncthreads();

    // ---------------- main loop: 24 segments --------------------------------------
#pragma unroll 1
    for (int seg = 0; seg < NSEG; ++seg) {
        // issue next-tile global loads (regs) BEFORE compute — latency hides under it
        float4 gn, kn, vn;
        if (seg < NSEG - 1) {
            gn = fetch(seg + 1);
            kn = ld4(Wk + (size_t)(seg + 1) * 4096 + (size_t)t * 4);
            vn = ld4(Wv + (size_t)(seg + 1) * 4096 + (size_t)t * 4);
        } else {
            // epilogue data: hidden row chunk, Wq, Wo
            gn = ld4(hidden + (size_t)(pbase + gr) * 64 + gc * 4);
            kn = ld4(Wq + (size_t)t * 4);
            vn = ld4(Wo + (size_t)t * 4);
        }

        // compute this segment from LDS
#pragma unroll
        for (int i0 = 0; i0 < 16; ++i0) {
            const float4 e = *reinterpret_cast<const float4*>(emb + p * 256 + ((i0 * 16) ^ psw));
#pragma unroll
            for (int u = 0; u < 4; ++u) {
                const int i = i0 * 4 + u;
                const float4 wk = ld4(&wk_lds[i][w4]);   // uniform -> LDS broadcast
                const float4 wv = ld4(&wv_lds[i][w4]);
                const float ev = (u == 0) ? e.x : (u == 1) ? e.y : (u == 2) ? e.z : e.w;
                kacc.x += ev * wk.x; kacc.y += ev * wk.y; kacc.z += ev * wk.z; kacc.w += ev * wk.w;
                vacc.x += ev * wv.x; vacc.y += ev * wv.y; vacc.z += ev * wv.z; vacc.w += ev * wv.w;
            }
        }
        __syncthreads();            // everyone done reading current tiles
        stage(gn, kn, vn);          // vmcnt waits here; loads had whole compute to land
        __syncthreads();            // staged tiles visible
    }

    // biases
    {
        const float4 bk4 = ld4(bk + w4);
        kacc.x += bk4.x; kacc.y += bk4.y; kacc.z += bk4.z; kacc.w += bk4.w;
        const float4 bv4 = ld4(bv + w4);
        vacc.x += bv4.x; vacc.y += bv4.y; vacc.z += bv4.z; vacc.w += bv4.w;
    }

    // ---------------- epilogue: q, gate, out --------------------------------------
    // emb = hidden (swizzled), wk_lds = Wq, wv_lds = Wo
    float4 qacc = ld4(bq + w4);
#pragma unroll
    for (int i0 = 0; i0 < 16; ++i0) {
        const float4 e = *reinterpret_cast<const float4*>(emb + p * 256 + ((i0 * 16) ^ psw));
#pragma unroll
        for (int u = 0; u < 4; ++u) {
            const int i = i0 * 4 + u;
            const float4 wq = ld4(&wk_lds[i][w4]);
            const float ev = (u == 0) ? e.x : (u == 1) ? e.y : (u == 2) ? e.z : e.w;
            qacc.x += ev * wq.x; qacc.y += ev * wq.y; qacc.z += ev * wq.z; qacc.w += ev * wq.w;
        }
    }
    gpart[t >> 6][p] = qacc.x * kacc.x + qacc.y * kacc.y + qacc.z * kacc.z + qacc.w * kacc.w;
    __syncthreads();                 // all q-phase reads of emb done
    // park v (transposed, swizzled) into emb
    *reinterpret_cast<float4*>(emb + p * 256 + ((w4 * 4) ^ psw)) = vacc;
    __syncthreads();

    float g = 0.0f;
#pragma unroll
    for (int j = 0; j < 16; ++j) g += gpart[j][p];
    const float gate = 1.0f / (1.0f + expf(-g * 0.125f));

    // out = gate * (v @ Wo) + bo   (wv_lds holds Wo)
    float4 oacc; oacc.x = oacc.y = oacc.z = oacc.w = 0.0f;
#pragma unroll
    for (int i0 = 0; i0 < 16; ++i0) {
        const float4 e = *reinterpret_cast<const float4*>(emb + p * 256 + ((i0 * 16) ^ psw));
#pragma unroll
        for (int u = 0; u < 4; ++u) {
            const int i = i0 * 4 + u;
            const float4 wo = ld4(&wv_lds[i][w4]);
            const float ev = (u == 0) ? e.x : (u == 1) ? e.y : (u == 2) ? e.z : e.w;
            oacc.x += ev * wo.x; oacc.y += ev * wo.y; oacc.z += ev * wo.z; oacc.w += ev * wo.w;
        }
    }
    const float4 bo4 = ld4(bo + w4);
    float4 res;
    res.x = gate * oacc.x + bo4.x;
    res.y = gate * oacc.y + bo4.y;
    res.z = gate * oacc.z + bo4.z;
    res.w = gate * oacc.w + bo4.w;
    *reinterpret_cast<float4*>(out + (size_t)(pbase + p) * 64 + w4) = res;

    if (t < POS_PER_WG) gate_out[pbase + t] = gate;
}

extern "C" void kernel_launch(void* const* d_in, const int* in_sizes, int n_in,
                              void* d_out, int out_size, void* d_ws, size_t ws_size,
                              hipStream_t stream) {
    const int*   tok    = (const int*)  d_in[0];
    const float* hidden = (const float*)d_in[1];
    const float* tab2   = (const float*)d_in[2];
    const int*   mul2   = (const int*)  d_in[3];
    const float* tab3   = (const float*)d_in[4];
    const int*   mul3   = (const int*)  d_in[5];
    const float* tab4   = (const float*)d_in[6];
    const int*   mul4   = (const int*)  d_in[7];
    const float* Wq     = (const float*)d_in[8];
    const float* bq     = (const float*)d_in[9];
    const float* Wk     = (const float*)d_in[10];
    const float* bk     = (const float*)d_in[11];
    const float* Wv     = (const float*)d_in[12];
    const float* bv     = (const float*)d_in[13];
    const float* Wo     = (const float*)d_in[14];
    const float* bo     = (const float*)d_in[15];

    float* out      = (float*)d_out;
    float* gate_out = out + (size_t)16384 * 64;   // B*S*D, then gate B*S

    hipLaunchKernelGGL(engram_fused, dim3(16384 / POS_PER_WG), dim3(1024), 0, stream,
                       tok, hidden, tab2, mul2, tab3, mul3, tab4, mul4,
                       Wq, bq, Wk, bk, Wv, bv, Wo, bo, out, gate_out);
}

// Round 3
// 102.051 us; speedup vs baseline: 2.7061x; 1.5575x over previous
//
#include <hip/hip_runtime.h>

#define SEQ  2048
#define NSEG 24          // 3 ngram sizes * 8 heads

typedef __bf16 bf16x8 __attribute__((ext_vector_type(8)));
typedef float  f32x4  __attribute__((ext_vector_type(4)));
typedef unsigned short u16x4 __attribute__((ext_vector_type(4)));
typedef unsigned short u16x8 __attribute__((ext_vector_type(8)));

__device__ __forceinline__ float4 ld4(const float* __restrict__ p) {
    return *reinterpret_cast<const float4*>(p);
}
__device__ __forceinline__ unsigned short f2bf(float f) {
    unsigned u = __float_as_uint(f);
    unsigned r = u + 0x7FFFu + ((u >> 16) & 1u);   // RNE
    return (unsigned short)(r >> 16);
}

// LDS pool layout (bytes):
//  buf b (b=0,1) @ b*24576 : emb +0 (8192) | wkT +8192 (8192) | wvT +16384 (8192)
//  idx   @ 49152  (int  [24][64])
//  gpart @ 55296  (float[4][64])
//  gate  @ 56320  (float[64])
#define LDS_BYTES 56576

__global__ __launch_bounds__(1024) void engram_mfma(
    const int*   __restrict__ tok,
    const float* __restrict__ hidden,
    const float* __restrict__ tab2, const int* __restrict__ mul2,
    const float* __restrict__ tab3, const int* __restrict__ mul3,
    const float* __restrict__ tab4, const int* __restrict__ mul4,
    const float* __restrict__ Wq, const float* __restrict__ bq,
    const float* __restrict__ Wk, const float* __restrict__ bk,
    const float* __restrict__ Wv, const float* __restrict__ bv,
    const float* __restrict__ Wo, const float* __restrict__ bo,
    float* __restrict__ out, float* __restrict__ gate_out)
{
    __shared__ __align__(16) char L[LDS_BYTES];
    int*   idx_lds  = (int*)  (L + 49152);
    float* gpart    = (float*)(L + 55296);
    float* gate_lds = (float*)(L + 56320);

    const int t     = threadIdx.x;
    const int pbase = blockIdx.x * 64;

    // ---------------- Phase 0: n-gram hash indices (exact int64 math) -------------
    if (t < 192) {
        const int grp = t >> 6;     // 0: n=2, 1: n=3, 2: n=4
        const int r   = t & 63;
        const int pos = pbase + r;
        const int s   = pos & (SEQ - 1);
        const int b   = pos >> 11;
        const int* tr = tok + (size_t)b * SEQ;
        const unsigned long long t3 = (unsigned long long)tr[s];
        const unsigned long long t2 = (s >= 1) ? (unsigned long long)tr[s - 1] : 0ull;
        const unsigned long long t1 = (s >= 2) ? (unsigned long long)tr[s - 2] : 0ull;
        const unsigned long long t0 = (s >= 3) ? (unsigned long long)tr[s - 3] : 0ull;
        if (grp == 0) {
            for (int h = 0; h < 8; ++h) {
                unsigned long long m = (unsigned long long)mul2[h];
                unsigned long long hh = (t2 * m + t3) % 100003ull;
                idx_lds[h * 64 + r] = (s >= 1) ? (int)hh : -1;
            }
        } else if (grp == 1) {
            for (int h = 0; h < 8; ++h) {
                unsigned long long m = (unsigned long long)mul3[h];
                unsigned long long hh = (t1 * m + t2) % 100019ull;
                hh = (hh * m + t3) % 100019ull;
                idx_lds[(8 + h) * 64 + r] = (s >= 2) ? (int)hh : -1;
            }
        } else {
            for (int h = 0; h < 8; ++h) {
                unsigned long long m = (unsigned long long)mul4[h];
                unsigned long long hh = (t0 * m + t1) % 100043ull;
                hh = (hh * m + t2) % 100043ull;
                hh = (hh * m + t3) % 100043ull;
                idx_lds[(16 + h) * 64 + r] = (s >= 3) ? (int)hh : -1;
            }
        }
    }
    __syncthreads();

    // staging roles
    const int gr = t >> 4;          // 0..63 : position row (emb)
    const int gc = t & 15;          // 0..15 : 4-float chunk within row
    const int tw  = t & 511;
    const int wcc = tw & 63;        // W output-col
    const int wkb = tw >> 6;        // 0..7 : 8-row k block
    const bool isK = (t < 512);

    // compute roles (wave tiling)
    const int l   = t & 63;
    const int wid = t >> 6;         // 0..15
    const int mt  = wid >> 2;       // M tile (positions)
    const int nt  = wid & 3;        // N tile (output cols)
    const int lg  = l >> 4;         // 16-lane group
    const int lc  = l & 15;

    const int swzA = (lc & 7) << 4;
    const int aoff0 = (mt * 16 + lc) * 128 + ((lg * 16) ^ swzA);
    const int aoff1 = (mt * 16 + lc) * 128 + ((64 + lg * 16) ^ swzA);
    const int boff0 = (nt * 16 + lc) * 128 + ((lg * 16) ^ swzA);
    const int boff1 = (nt * 16 + lc) * 128 + ((64 + lg * 16) ^ swzA);

    auto fetch = [&](int seg) -> float4 {
        if (seg == NSEG)
            return ld4(hidden + (size_t)(pbase + gr) * 64 + gc * 4);
        const int idx = idx_lds[seg * 64 + gr];
        float4 z; z.x = z.y = z.z = z.w = 0.0f;
        if (idx < 0) return z;
        const int ni = seg >> 3, h = seg & 7;
        const float* tabp; int prime;
        if (ni == 0)      { tabp = tab2; prime = 100003; }
        else if (ni == 1) { tabp = tab3; prime = 100019; }
        else              { tabp = tab4; prime = 100043; }
        return ld4(tabp + ((size_t)h * prime + idx) * 64 + gc * 4);
    };

    auto loadW = [&](int seg, float* w8) {
        const float* W;
        int row0;
        if (seg == NSEG) { W = isK ? Wq : Wo; row0 = 0; }
        else             { W = isK ? Wk : Wv; row0 = seg * 64; }
        const float* p = W + (size_t)(row0 + wkb * 8) * 64 + wcc;
#pragma unroll
        for (int kk = 0; kk < 8; ++kk) w8[kk] = p[(size_t)kk * 64];
    };

    auto stage = [&](int buf, const float4& g, const float* w8) {
        char* B = L + buf * 24576;
        u16x4 e; e[0] = f2bf(g.x); e[1] = f2bf(g.y); e[2] = f2bf(g.z); e[3] = f2bf(g.w);
        *(u16x4*)(B + gr * 128 + ((gc * 8) ^ ((gr & 7) << 4))) = e;
        u16x8 wv8;
#pragma unroll
        for (int kk = 0; kk < 8; ++kk) wv8[kk] = f2bf(w8[kk]);
        char* Wb = B + (isK ? 8192 : 16384);
        *(u16x8*)(Wb + wcc * 128 + ((wkb * 16) ^ ((wcc & 7) << 4))) = wv8;
    };

    f32x4 kacc = {0.f, 0.f, 0.f, 0.f};
    f32x4 vacc = {0.f, 0.f, 0.f, 0.f};

    // ---------------- prologue ----------------------------------------------------
    float4 rg, rgN;
    float  w8[8], w8N[8];
    rg = fetch(0); loadW(0, w8);
    stage(0, rg, w8);               // vmcnt drain (one-time)
    rg = fetch(1); loadW(1, w8);
    __syncthreads();                // buf0 ready

    // ---------------- main loop: one barrier per segment --------------------------
#pragma unroll 1
    for (int seg = 0; seg < NSEG; ++seg) {
        if (seg + 2 <= NSEG) { rgN = fetch(seg + 2); loadW(seg + 2, w8N); }
        stage((seg + 1) & 1, rg, w8);         // write NEXT buffer (safe: barrier'd)

        const char* B = L + (seg & 1) * 24576;
        bf16x8 a0 = *(const bf16x8*)(B + aoff0);
        bf16x8 a1 = *(const bf16x8*)(B + aoff1);
        bf16x8 k0 = *(const bf16x8*)(B + 8192  + boff0);
        bf16x8 k1 = *(const bf16x8*)(B + 8192  + boff1);
        bf16x8 v0 = *(const bf16x8*)(B + 16384 + boff0);
        bf16x8 v1 = *(const bf16x8*)(B + 16384 + boff1);
        kacc = __builtin_amdgcn_mfma_f32_16x16x32_bf16(a0, k0, kacc, 0, 0, 0);
        kacc = __builtin_amdgcn_mfma_f32_16x16x32_bf16(a1, k1, kacc, 0, 0, 0);
        vacc = __builtin_amdgcn_mfma_f32_16x16x32_bf16(a0, v0, vacc, 0, 0, 0);
        vacc = __builtin_amdgcn_mfma_f32_16x16x32_bf16(a1, v1, vacc, 0, 0, 0);

        __syncthreads();
        rg = rgN;
#pragma unroll
        for (int kk = 0; kk < 8; ++kk) w8[kk] = w8N[kk];
    }

    // ---------------- epilogue ----------------------------------------------------
    // buf0 now holds: emb=hidden(bf16), wkT=WqT, wvT=WoT
    const int   c16 = nt * 16 + lc;
    const float bkc = bk[c16], bvc = bv[c16], bqc = bq[c16], boc = bo[c16];
#pragma unroll
    for (int r = 0; r < 4; ++r) { kacc[r] += bkc; vacc[r] += bvc; }

    const char* B0 = L;
    f32x4 qacc = {0.f, 0.f, 0.f, 0.f};
    {
        bf16x8 a0 = *(const bf16x8*)(B0 + aoff0);
        bf16x8 a1 = *(const bf16x8*)(B0 + aoff1);
        bf16x8 q0 = *(const bf16x8*)(B0 + 8192 + boff0);
        bf16x8 q1 = *(const bf16x8*)(B0 + 8192 + boff1);
        qacc = __builtin_amdgcn_mfma_f32_16x16x32_bf16(a0, q0, qacc, 0, 0, 0);
        qacc = __builtin_amdgcn_mfma_f32_16x16x32_bf16(a1, q1, qacc, 0, 0, 0);
    }
    float pr[4];
#pragma unroll
    for (int r = 0; r < 4; ++r) pr[r] = (qacc[r] + bqc) * kacc[r];
#pragma unroll
    for (int m = 1; m < 16; m <<= 1) {
#pragma unroll
        for (int r = 0; r < 4; ++r) pr[r] += __shfl_xor(pr[r], m, 64);
    }
    if (lc == 0) {
        f32x4 pv = {pr[0], pr[1], pr[2], pr[3]};
        *(f32x4*)(gpart + nt * 64 + mt * 16 + lg * 4) = pv;
    }
    __syncthreads();

    if (t < 64) {
        const float s = gpart[t] + gpart[64 + t] + gpart[128 + t] + gpart[192 + t];
        const float gt = 1.0f / (1.0f + expf(-s * 0.125f));
        gate_lds[t] = gt;
        gate_out[pbase + t] = gt;
    }
    __syncthreads();

    // write gate*v (bf16) into buf1.emb
    char* E1 = L + 24576;
#pragma unroll
    for (int r = 0; r < 4; ++r) {
        const int row = mt * 16 + lg * 4 + r;
        const float gv = gate_lds[row] * vacc[r];
        *(unsigned short*)(E1 + row * 128 + ((nt * 32 + lc * 2) ^ ((row & 7) << 4))) = f2bf(gv);
    }
    __syncthreads();

    f32x4 oacc = {0.f, 0.f, 0.f, 0.f};
    {
        bf16x8 a0 = *(const bf16x8*)(E1 + aoff0);
        bf16x8 a1 = *(const bf16x8*)(E1 + aoff1);
        bf16x8 o0 = *(const bf16x8*)(B0 + 16384 + boff0);
        bf16x8 o1 = *(const bf16x8*)(B0 + 16384 + boff1);
        oacc = __builtin_amdgcn_mfma_f32_16x16x32_bf16(a0, o0, oacc, 0, 0, 0);
        oacc = __builtin_amdgcn_mfma_f32_16x16x32_bf16(a1, o1, oacc, 0, 0, 0);
    }
#pragma unroll
    for (int r = 0; r < 4; ++r) {
        const int row = mt * 16 + lg * 4 + r;
        out[(size_t)(pbase + row) * 64 + c16] = oacc[r] + boc;
    }
}

extern "C" void kernel_launch(void* const* d_in, const int* in_sizes, int n_in,
                              void* d_out, int out_size, void* d_ws, size_t ws_size,
                              hipStream_t stream) {
    const int*   tok    = (const int*)  d_in[0];
    const float* hidden = (const float*)d_in[1];
    const float* tab2   = (const float*)d_in[2];
    const int*   mul2   = (const int*)  d_in[3];
    const float* tab3   = (const float*)d_in[4];
    const int*   mul3   = (const int*)  d_in[5];
    const float* tab4   = (const float*)d_in[6];
    const int*   mul4   = (const int*)  d_in[7];
    const float* Wq     = (const float*)d_in[8];
    const float* bq     = (const float*)d_in[9];
    const float* Wk     = (const float*)d_in[10];
    const float* bk     = (const float*)d_in[11];
    const float* Wv     = (const float*)d_in[12];
    const float* bv     = (const float*)d_in[13];
    const float* Wo     = (const float*)d_in[14];
    const float* bo     = (const float*)d_in[15];

    float* out      = (float*)d_out;
    float* gate_out = out + (size_t)16384 * 64;   // B*S*D, then gate B*S

    hipLaunchKernelGGL(engram_mfma, dim3(256), dim3(1024), 0, stream,
                       tok, hidden, tab2, mul2, tab3, mul3, tab4, mul4,
                       Wq, bq, Wk, bk, Wv, bv, Wo, bo, out, gate_out);
}

// Round 4
// 81.380 us; speedup vs baseline: 3.3934x; 1.2540x over previous
//
#include <hip/hip_runtime.h>

#define SEQ  2048
#define NSEG 24
#define POS  32

typedef __bf16 bf16x8 __attribute__((ext_vector_type(8)));
typedef float  f32x4  __attribute__((ext_vector_type(4)));
typedef unsigned short ushort8 __attribute__((ext_vector_type(8)));

// d_ws layout (bytes): [0,256) zero row (fp32); then bf16 B-fragment blocks
#define WS_K 256
#define WS_V (256 + 196608)
#define WS_Q (256 + 393216)
#define WS_O (256 + 393216 + 8192)
// total 409856 bytes

__device__ __forceinline__ unsigned short f2bf(float f) {
    unsigned u = __float_as_uint(f);
    unsigned r = u + 0x7FFFu + ((u >> 16) & 1u);   // RNE
    return (unsigned short)(r >> 16);
}

__device__ __forceinline__ void gload16(const void* g, void* l) {
    __builtin_amdgcn_global_load_lds(
        (const __attribute__((address_space(1))) unsigned int*)g,
        (__attribute__((address_space(3))) unsigned int*)l,
        16, 0, 0);
}

// ---------------- prep: weights -> bf16 B-fragment layout in ws ----------------
// fragment item index it = sh*256 + nt*64 + lg*16 + lc ; bytes at base + it*16
// holds W[sh*32 + lg*8 + j][nt*16 + lc] for j=0..7  (sh = seg*2 + half)
__global__ __launch_bounds__(256) void prep_ws(
    const float* __restrict__ Wk, const float* __restrict__ Wv,
    const float* __restrict__ Wq, const float* __restrict__ Wo,
    char* __restrict__ ws)
{
    const int tid = blockIdx.x * 256 + threadIdx.x;
    if (tid < 64) ((float*)ws)[tid] = 0.0f;          // zero row for masked gathers
    const float* W; char* base; int it = tid;
    if      (it < 12288) { W = Wk; base = ws + WS_K; }
    else if (it < 24576) { W = Wv; base = ws + WS_V; it -= 12288; }
    else if (it < 25088) { W = Wq; base = ws + WS_Q; it -= 24576; }
    else if (it < 25600) { W = Wo; base = ws + WS_O; it -= 25088; }
    else return;
    const int lc = it & 15, lg = (it >> 4) & 3, nt = (it >> 6) & 3, sh = it >> 8;
    const int col = nt * 16 + lc;
    const int k0  = sh * 32 + lg * 8;
    ushort8 v;
#pragma unroll
    for (int j = 0; j < 8; ++j) v[j] = f2bf(W[(size_t)(k0 + j) * 64 + col]);
    *(ushort8*)(base + (size_t)it * 16) = v;
}

// ---------------- main fused kernel -------------------------------------------
// LDS: emb[2][32 rows][256B fp32, chunk-XOR swizzled] | idx[24][32] | gpart[4][32] | gate[32]
#define LDS_BYTES 20096

__global__ __launch_bounds__(256, 8) void engram_main(
    const int*   __restrict__ tok,
    const float* __restrict__ hidden,
    const float* __restrict__ tab2, const int* __restrict__ mul2,
    const float* __restrict__ tab3, const int* __restrict__ mul3,
    const float* __restrict__ tab4, const int* __restrict__ mul4,
    const float* __restrict__ bq, const float* __restrict__ bk,
    const float* __restrict__ bv, const float* __restrict__ bo,
    const char*  __restrict__ ws,
    float* __restrict__ out, float* __restrict__ gate_out)
{
    __shared__ __align__(16) char L[LDS_BYTES];
    int*   idxl  = (int*)  (L + 16384);
    float* gpart = (float*)(L + 19456);
    float* gatel = (float*)(L + 19968);

    const int t     = threadIdx.x;
    const int pbase = blockIdx.x * POS;

    // ---- hash phase: 8 hsel x 32 positions, each thread does 3 chains --------
    {
        const int r    = t & 31;
        const int hsel = t >> 5;
        const int pos  = pbase + r;
        const int s    = pos & (SEQ - 1);
        const int b    = pos >> 11;
        const int* tr  = tok + (size_t)b * SEQ;
        const unsigned long long t3 = (unsigned long long)tr[s];
        const unsigned long long t2 = (s >= 1) ? (unsigned long long)tr[s - 1] : 0ull;
        const unsigned long long t1 = (s >= 2) ? (unsigned long long)tr[s - 2] : 0ull;
        const unsigned long long t0 = (s >= 3) ? (unsigned long long)tr[s - 3] : 0ull;
        {
            unsigned long long m = (unsigned long long)mul2[hsel];
            unsigned long long hh = (t2 * m + t3) % 100003ull;
            idxl[hsel * 32 + r] = (s >= 1) ? (int)hh : -1;
        }
        {
            unsigned long long m = (unsigned long long)mul3[hsel];
            unsigned long long hh = (t1 * m + t2) % 100019ull;
            hh = (hh * m + t3) % 100019ull;
            idxl[(8 + hsel) * 32 + r] = (s >= 2) ? (int)hh : -1;
        }
        {
            unsigned long long m = (unsigned long long)mul4[hsel];
            unsigned long long hh = (t0 * m + t1) % 100043ull;
            hh = (hh * m + t2) % 100043ull;
            hh = (hh * m + t3) % 100043ull;
            idxl[(16 + hsel) * 32 + r] = (s >= 3) ? (int)hh : -1;
        }
    }
    __syncthreads();

    const int lam = t & 63;
    const int w   = t >> 6;           // wave id == nt (output col block)
    const int lg  = lam >> 4, lc = lam & 15;

    // gather seg's rows into emb[buf] via global_load_lds, source-chunk XOR so
    // LDS content is swizzled while the DMA destination stays linear
    auto gather = [&](int seg, int buf) {
        char* wb = L + buf * 8192 + w * 2048;
#pragma unroll
        for (int i = 0; i < 2; ++i) {
            const int lrow = w * 8 + i * 4 + (lam >> 4);
            const float* rowp;
            if (seg == NSEG) {
                rowp = hidden + (size_t)(pbase + lrow) * 64;
            } else {
                const int ix = idxl[seg * 32 + lrow];
                const int ni = seg >> 3, h = seg & 7;
                const float* tabp; int prime;
                if (ni == 0)      { tabp = tab2; prime = 100003; }
                else if (ni == 1) { tabp = tab3; prime = 100019; }
                else              { tabp = tab4; prime = 100043; }
                rowp = (ix < 0) ? (const float*)ws
                                : tabp + ((size_t)h * prime + ix) * 64;
            }
            const float* src = rowp + (((lam & 15) ^ (lrow & 7)) << 2);
            gload16(src, wb + i * 1024 + lam * 16);
        }
    };

    // A-fragment: fp32 from swizzled LDS -> bf16 (hw cvt)
    auto loadA = [&](const char* eb, int mt, int half) -> bf16x8 {
        const int row = mt * 16 + lc;
        const int swz = (row & 7) << 4;
        const char* p = eb + row * 256;
        const f32x4 x0 = *(const f32x4*)(p + ((half * 128 + lg * 32) ^ swz));
        const f32x4 x1 = *(const f32x4*)(p + ((half * 128 + lg * 32 + 16) ^ swz));
        bf16x8 a;
        a[0] = (__bf16)x0[0]; a[1] = (__bf16)x0[1]; a[2] = (__bf16)x0[2]; a[3] = (__bf16)x0[3];
        a[4] = (__bf16)x1[0]; a[5] = (__bf16)x1[1]; a[6] = (__bf16)x1[2]; a[7] = (__bf16)x1[3];
        return a;
    };

    // B-fragment straight from ws (L2-resident, lane-contiguous 16B)
    auto loadB = [&](int wsoff, int sh) -> bf16x8 {
        return *(const bf16x8*)(ws + wsoff +
                 (size_t)(sh * 4096 + w * 1024 + lg * 256 + lc * 16));
    };

    f32x4 kacc0 = {0.f,0.f,0.f,0.f}, kacc1 = {0.f,0.f,0.f,0.f};
    f32x4 vacc0 = {0.f,0.f,0.f,0.f}, vacc1 = {0.f,0.f,0.f,0.f};

    gather(0, 0);
    __syncthreads();

#pragma unroll 1
    for (int seg = 0; seg < NSEG; ++seg) {
        gather(seg + 1, (seg + 1) & 1);          // async into other buffer
        const char* eb = L + (seg & 1) * 8192;
        const bf16x8 k0 = loadB(WS_K, seg * 2 + 0);
        const bf16x8 k1 = loadB(WS_K, seg * 2 + 1);
        const bf16x8 v0 = loadB(WS_V, seg * 2 + 0);
        const bf16x8 v1 = loadB(WS_V, seg * 2 + 1);
        {
            const bf16x8 a0 = loadA(eb, 0, 0);
            const bf16x8 a1 = loadA(eb, 0, 1);
            kacc0 = __builtin_amdgcn_mfma_f32_16x16x32_bf16(a0, k0, kacc0, 0, 0, 0);
            kacc0 = __builtin_amdgcn_mfma_f32_16x16x32_bf16(a1, k1, kacc0, 0, 0, 0);
            vacc0 = __builtin_amdgcn_mfma_f32_16x16x32_bf16(a0, v0, vacc0, 0, 0, 0);
            vacc0 = __builtin_amdgcn_mfma_f32_16x16x32_bf16(a1, v1, vacc0, 0, 0, 0);
        }
        {
            const bf16x8 a0 = loadA(eb, 1, 0);
            const bf16x8 a1 = loadA(eb, 1, 1);
            kacc1 = __builtin_amdgcn_mfma_f32_16x16x32_bf16(a0, k0, kacc1, 0, 0, 0);
            kacc1 = __builtin_amdgcn_mfma_f32_16x16x32_bf16(a1, k1, kacc1, 0, 0, 0);
            vacc1 = __builtin_amdgcn_mfma_f32_16x16x32_bf16(a0, v0, vacc1, 0, 0, 0);
            vacc1 = __builtin_amdgcn_mfma_f32_16x16x32_bf16(a1, v1, vacc1, 0, 0, 0);
        }
        __syncthreads();
    }

    // ---- epilogue: biases, q, gate, gated PV ---------------------------------
    const int   c   = w * 16 + lc;
    const float bkc = bk[c], bvc = bv[c], bqc = bq[c], boc = bo[c];
#pragma unroll
    for (int r = 0; r < 4; ++r) {
        kacc0[r] += bkc; kacc1[r] += bkc;
        vacc0[r] += bvc; vacc1[r] += bvc;
    }

    const char* H = L;                 // hidden staged into buf0 at seg=23
    f32x4 q0 = {0.f,0.f,0.f,0.f}, q1 = {0.f,0.f,0.f,0.f};
    {
        const bf16x8 wq0 = loadB(WS_Q, 0);
        const bf16x8 wq1 = loadB(WS_Q, 1);
        bf16x8 a0 = loadA(H, 0, 0), a1 = loadA(H, 0, 1);
        q0 = __builtin_amdgcn_mfma_f32_16x16x32_bf16(a0, wq0, q0, 0, 0, 0);
        q0 = __builtin_amdgcn_mfma_f32_16x16x32_bf16(a1, wq1, q0, 0, 0, 0);
        a0 = loadA(H, 1, 0); a1 = loadA(H, 1, 1);
        q1 = __builtin_amdgcn_mfma_f32_16x16x32_bf16(a0, wq0, q1, 0, 0, 0);
        q1 = __builtin_amdgcn_mfma_f32_16x16x32_bf16(a1, wq1, q1, 0, 0, 0);
    }
    float pr0[4], pr1[4];
#pragma unroll
    for (int r = 0; r < 4; ++r) {
        pr0[r] = (q0[r] + bqc) * kacc0[r];
        pr1[r] = (q1[r] + bqc) * kacc1[r];
    }
#pragma unroll
    for (int m = 1; m < 16; m <<= 1) {
#pragma unroll
        for (int r = 0; r < 4; ++r) {
            pr0[r] += __shfl_xor(pr0[r], m, 64);
            pr1[r] += __shfl_xor(pr1[r], m, 64);
        }
    }
    if (lc == 0) {
        f32x4 a = {pr0[0], pr0[1], pr0[2], pr0[3]};
        f32x4 b = {pr1[0], pr1[1], pr1[2], pr1[3]};
        *(f32x4*)(gpart + w * 32 + lg * 4)      = a;
        *(f32x4*)(gpart + w * 32 + 16 + lg * 4) = b;
    }
    __syncthreads();

    if (t < 32) {
        const float s  = gpart[t] + gpart[32 + t] + gpart[64 + t] + gpart[96 + t];
        const float gt = 1.0f / (1.0f + expf(-s * 0.125f));
        gatel[t] = gt;
        gate_out[pbase + t] = gt;
    }
    __syncthreads();

    // stage gate*v (fp32, swizzled) into buf1
    char* E1 = L + 8192;
    const int cb = c << 2;
    const int chunkpart = cb & ~15, lowpart = cb & 15;
#pragma unroll
    for (int r = 0; r < 4; ++r) {
        const int row0 = lg * 4 + r;
        *(float*)(E1 + row0 * 256 + ((chunkpart ^ ((row0 & 7) << 4)) | lowpart))
            = gatel[row0] * vacc0[r];
        const int row1 = 16 + lg * 4 + r;
        *(float*)(E1 + row1 * 256 + ((chunkpart ^ ((row1 & 7) << 4)) | lowpart))
            = gatel[row1] * vacc1[r];
    }
    __syncthreads();

    f32x4 o0 = {0.f,0.f,0.f,0.f}, o1 = {0.f,0.f,0.f,0.f};
    {
        const bf16x8 wo0 = loadB(WS_O, 0);
        const bf16x8 wo1 = loadB(WS_O, 1);
        bf16x8 a0 = loadA(E1, 0, 0), a1 = loadA(E1, 0, 1);
        o0 = __builtin_amdgcn_mfma_f32_16x16x32_bf16(a0, wo0, o0, 0, 0, 0);
        o0 = __builtin_amdgcn_mfma_f32_16x16x32_bf16(a1, wo1, o0, 0, 0, 0);
        a0 = loadA(E1, 1, 0); a1 = loadA(E1, 1, 1);
        o1 = __builtin_amdgcn_mfma_f32_16x16x32_bf16(a0, wo0, o1, 0, 0, 0);
        o1 = __builtin_amdgcn_mfma_f32_16x16x32_bf16(a1, wo1, o1, 0, 0, 0);
    }
#pragma unroll
    for (int r = 0; r < 4; ++r) {
        const int row0 = lg * 4 + r;
        out[(size_t)(pbase + row0) * 64 + c] = o0[r] + boc;
        const int row1 = 16 + lg * 4 + r;
        out[(size_t)(pbase + row1) * 64 + c] = o1[r] + boc;
    }
}

extern "C" void kernel_launch(void* const* d_in, const int* in_sizes, int n_in,
                              void* d_out, int out_size, void* d_ws, size_t ws_size,
                              hipStream_t stream) {
    const int*   tok    = (const int*)  d_in[0];
    const float* hidden = (const float*)d_in[1];
    const float* tab2   = (const float*)d_in[2];
    const int*   mul2   = (const int*)  d_in[3];
    const float* tab3   = (const float*)d_in[4];
    const int*   mul3   = (const int*)  d_in[5];
    const float* tab4   = (const float*)d_in[6];
    const int*   mul4   = (const int*)  d_in[7];
    const float* Wq     = (const float*)d_in[8];
    const float* bq     = (const float*)d_in[9];
    const float* Wk     = (const float*)d_in[10];
    const float* bk     = (const float*)d_in[11];
    const float* Wv     = (const float*)d_in[12];
    const float* bv     = (const float*)d_in[13];
    const float* Wo     = (const float*)d_in[14];
    const float* bo     = (const float*)d_in[15];

    float* out      = (float*)d_out;
    float* gate_out = out + (size_t)16384 * 64;   // B*S*D, then gate B*S

    hipLaunchKernelGGL(prep_ws, dim3(100), dim3(256), 0, stream,
                       Wk, Wv, Wq, Wo, (char*)d_ws);
    hipLaunchKernelGGL(engram_main, dim3(16384 / POS), dim3(256), 0, stream,
                       tok, hidden, tab2, mul2, tab3, mul3, tab4, mul4,
                       bq, bk, bv, bo, (const char*)d_ws, out, gate_out);
}